// Round 8
// baseline (119.182 us; speedup 1.0000x reference)
//
#include <hip/hip_runtime.h>

// Problem constants (match reference)
#define BB 64
#define PP 8400
#define TT 100
#define TG 5                      // targets per block
#define NGRP (TT / TG)            // 20 target-groups per batch
#define NSPLIT 2                  // P-range split per (b, grp)
#define NBLK (BB * NGRP * NSPLIT) // 2560 blocks -> 10/CU nominal, HW caps 8/CU
#define NGROUPS8 (PP / 8)         // 1050 8-box groups
#define GRPH (NGROUPS8 / NSPLIT)  // 525 groups per half (4200 boxes)
#define NE (BB * TT)              // 6400 (b,t) pairs

// Kernel 1: one block per (batch, 5-target-group, P-half). Branchless exact
// IEEE-div IoU (bit-match numpy), in-block first-occurrence argmax over this
// half's 4200 boxes. Writes (best,idx) per target-half; NO sq / lengths here.
// XCD swizzle keeps each batch's panels on one XCD's L2 (8 panels = 1.34 MB).
__global__ __launch_bounds__(256) void yolo_match_kernel(
    const float* __restrict__ pred,    // [B, P, 5]
    const float* __restrict__ tgt,     // [B, T, 5]
    float*       __restrict__ wsbest,  // [NE * NSPLIT]
    int*         __restrict__ wsidx)   // [NE * NSPLIT]
{
#pragma clang fp contract(off)
    // Decode: block i -> XCD (i % 8); all 40 (grp,half) blocks of batch b
    // share one XCD.
    const int blkraw = blockIdx.x;
    const int x    = blkraw & 7;
    const int r    = blkraw >> 3;               // 0..319
    const int bhi  = r / (NGRP * NSPLIT);       // 0..7
    const int rem  = r - bhi * (NGRP * NSPLIT); // 0..39
    const int grp  = rem / NSPLIT;              // 0..19
    const int half = rem - grp * NSPLIT;        // 0..1
    const int b    = x + 8 * bhi;               // 0..63
    const int t0   = grp * TG;
    const int tid  = threadIdx.x;
    const int lane = tid & 63;
    const int wid  = tid >> 6;                  // 0..3

    const float*  pb  = pred + (size_t)b * PP * 5;
    const float4* pb4 = (const float4*)pb;
    const float*  tb  = tgt + ((size_t)b * TT + t0) * 5;

    // Per-target corners + area in registers.
    float tx1[TG], ty1[TG], tx2[TG], ty2[TG], ta[TG];
#pragma unroll
    for (int g = 0; g < TG; ++g) {
        const float tcx = tb[g * 5 + 1], tcy = tb[g * 5 + 2];
        const float tw  = tb[g * 5 + 3], th  = tb[g * 5 + 4];
        tx1[g] = tcx - tw * 0.5f;
        ty1[g] = tcy - th * 0.5f;
        tx2[g] = tcx + tw * 0.5f;
        ty2[g] = tcy + th * 0.5f;
        ta[g]  = (tx2[g] - tx1[g]) * (ty2[g] - ty1[g]);
    }

    float best[TG];
    int   bidx[TG];
#pragma unroll
    for (int g = 0; g < TG; ++g) { best[g] = -1.0f; bidx[g] = 0; }

    // This half's range: 8 boxes per step via 10 aligned float4 loads.
    const int gbeg = half * GRPH;
    const int gend = gbeg + GRPH;
    for (int g0 = gbeg + tid; g0 < gend; g0 += 256) {
        float4 q[10];
#pragma unroll
        for (int k = 0; k < 10; ++k) q[k] = pb4[g0 * 10 + k];

        float cxs[8], cys[8], wss[8], hss[8];
#pragma unroll
        for (int h = 0; h < 2; ++h) {      // two 4-box halves, same pattern
            const float4 v0 = q[5 * h + 0];
            const float4 v1 = q[5 * h + 1];
            const float4 v2 = q[5 * h + 2];
            const float4 v3 = q[5 * h + 3];
            const float4 v4 = q[5 * h + 4];
            cxs[4 * h + 0] = v0.y; cys[4 * h + 0] = v0.z; wss[4 * h + 0] = v0.w; hss[4 * h + 0] = v1.x;
            cxs[4 * h + 1] = v1.z; cys[4 * h + 1] = v1.w; wss[4 * h + 1] = v2.x; hss[4 * h + 1] = v2.y;
            cxs[4 * h + 2] = v2.w; cys[4 * h + 2] = v3.x; wss[4 * h + 2] = v3.y; hss[4 * h + 2] = v3.z;
            cxs[4 * h + 3] = v4.x; cys[4 * h + 3] = v4.y; wss[4 * h + 3] = v4.z; hss[4 * h + 3] = v4.w;
        }

#pragma unroll
        for (int j = 0; j < 8; ++j) {
            const float px1 = cxs[j] - wss[j] * 0.5f;
            const float py1 = cys[j] - hss[j] * 0.5f;
            const float px2 = cxs[j] + wss[j] * 0.5f;
            const float py2 = cys[j] + hss[j] * 0.5f;
            const float area_p = (px2 - px1) * (py2 - py1);
            const int   p = g0 * 8 + j;             // global box index

#pragma unroll
            for (int g = 0; g < TG; ++g) {
                const float ix1 = fmaxf(px1, tx1[g]);
                const float iy1 = fmaxf(py1, ty1[g]);
                const float ix2 = fminf(px2, tx2[g]);
                const float iy2 = fminf(py2, ty2[g]);
                const float inter = fmaxf(ix2 - ix1, 0.0f) * fmaxf(iy2 - iy1, 0.0f);
                // numpy eval order: ((area_p + area_t) - inter) + 1e-6
                const float denom = ((area_p + ta[g]) - inter) + 1e-6f;
                const float iou   = inter / denom;   // IEEE div — bit-match numpy
                if (iou > best[g]) { best[g] = iou; bidx[g] = p; }  // -> cndmask
            }
        }
    }

    // Argmax reduce: wave shuffle, then cross-wave via LDS; first-occurrence
    // preserved (per-lane candidates ascending; tie -> lower index).
    __shared__ float s_best[4][TG];
    __shared__ int   s_bidx[4][TG];

#pragma unroll
    for (int g = 0; g < TG; ++g) {
        float bv = best[g];
        int   bi = bidx[g];
        for (int off = 32; off > 0; off >>= 1) {
            const float ob = __shfl_down(bv, off, 64);
            const int   oi = __shfl_down(bi, off, 64);
            if (ob > bv || (ob == bv && oi < bi)) { bv = ob; bi = oi; }
        }
        if (lane == 0) { s_best[wid][g] = bv; s_bidx[wid][g] = bi; }
    }
    __syncthreads();

    if (tid < TG) {
        const int g = tid;
        float bv = s_best[0][g];
        int   bi = s_bidx[0][g];
#pragma unroll
        for (int w = 1; w < 4; ++w) {
            const float ob = s_best[w][g];
            const int   oi = s_bidx[w][g];
            if (ob > bv || (ob == bv && oi < bi)) { bv = ob; bi = oi; }
        }
        const int e = ((b * TT + t0 + g) << 1) | half;
        wsbest[e] = bv;
        wsidx[e]  = bi;
    }
}

// Kernel 2: single block. Combine halves per (b,t) (tie -> half 0 = lower
// indices = first occurrence), gather matched prediction, masked sq, sum.
__global__ __launch_bounds__(1024) void yolo_finish_kernel(
    const float* __restrict__ pred,
    const float* __restrict__ tgt,
    const int*   __restrict__ lengths,
    const float* __restrict__ wsbest,
    const int*   __restrict__ wsidx,
    float*       __restrict__ out)
{
#pragma clang fp contract(off)
    const int tid = threadIdx.x;
    float acc = 0.0f;

    for (int e = tid; e < NE; e += 1024) {
        const int b = e / TT;
        const int t = e - b * TT;
        const float b0 = wsbest[2 * e + 0];
        const float b1 = wsbest[2 * e + 1];
        const int   i0 = wsidx[2 * e + 0];
        const int   i1 = wsidx[2 * e + 1];
        const int   bi = (b1 > b0) ? i1 : i0;   // equal -> half 0 (lower idx)

        const float* mp = pred + ((size_t)b * PP + bi) * 5;
        const float* tp = tgt  + ((size_t)b * TT + t) * 5;
        float sq = 0.0f;
        for (int k = 0; k < 5; ++k) {
            const float d = mp[k] - tp[k];
            sq += d * d;
        }
        acc += (t < lengths[b]) ? sq : 0.0f;
    }

    __shared__ float sm[1024];
    sm[tid] = acc;
    __syncthreads();
    for (int off = 512; off > 0; off >>= 1) {
        if (tid < off) sm[tid] += sm[tid + off];
        __syncthreads();
    }
    if (tid == 0) out[0] = sm[0] / (float)BB;
}

extern "C" void kernel_launch(void* const* d_in, const int* in_sizes, int n_in,
                              void* d_out, int out_size, void* d_ws, size_t ws_size,
                              hipStream_t stream) {
    const float* pred    = (const float*)d_in[0]; // [B,P,5] f32
    const float* tgt     = (const float*)d_in[1]; // [B,T,5] f32
    const int*   lengths = (const int*)d_in[2];   // [B]
    float* out = (float*)d_out;

    float* wsbest = (float*)d_ws;                 // NE*NSPLIT floats
    int*   wsidx  = (int*)d_ws + NE * NSPLIT;     // NE*NSPLIT ints (102.4 KB total)

    yolo_match_kernel<<<NBLK, 256, 0, stream>>>(pred, tgt, wsbest, wsidx);
    yolo_finish_kernel<<<1, 1024, 0, stream>>>(pred, tgt, lengths,
                                               wsbest, wsidx, out);
}

// Round 9
// 109.232 us; speedup vs baseline: 1.0911x; 1.0911x over previous
//
#include <hip/hip_runtime.h>

// Problem constants (match reference)
#define BB 64
#define PP 8400
#define TT 100
#define TG 5             // targets per block
#define NGRP (TT / TG)   // 20 groups per batch -> grid = 64*20 = 1280
#define NBLK (BB * NGRP)
#define NE (BB * TT)     // 6400 (b,t) pairs

// Kernel 1: one block per (batch, 5-target-group). DIVISION-FREE argmax:
// IoU ratios compared by cross-multiplication (a/b > c/d <=> a*d > c*b for
// positive denom; denom = area_p+area_t-inter+1e-6 > 0 always). Removes the
// IEEE-div expansion (VCC serialization + quarter-rate rcp) that capped
// rounds 4-8 at ~49us. Ties -> lower index (first occurrence). Near-tie
// (<2ulp) selections may differ from numpy's rounded-quotient argmax; error
// impact ~0.03 << 0.151 threshold (see round-9 analysis).
__global__ __launch_bounds__(256) void yolo_match_kernel(
    const float* __restrict__ pred,    // [B, P, 5]
    const float* __restrict__ tgt,     // [B, T, 5]
    int*         __restrict__ wsidx)   // [NE] best index per (b,t)
{
#pragma clang fp contract(off)
    // XCD-aware decode: block i -> XCD (i % 8); all 20 groups of batch b
    // land on one XCD. 160 blocks/XCD = 8 panels = 1.34 MB << 4 MB L2.
    const int blkraw = blockIdx.x;
    const int x    = blkraw & 7;
    const int r    = blkraw >> 3;          // 0..159
    const int bhi  = r / NGRP;             // 0..7
    const int grp  = r - bhi * NGRP;       // 0..19
    const int b    = x + 8 * bhi;          // 0..63
    const int t0   = grp * TG;
    const int tid  = threadIdx.x;
    const int lane = tid & 63;
    const int wid  = tid >> 6;             // 0..3

    const float*  pb  = pred + (size_t)b * PP * 5;
    const float4* pb4 = (const float4*)pb;
    const float*  tb  = tgt + ((size_t)b * TT + t0) * 5;

    // Per-target corners + area in registers.
    float tx1[TG], ty1[TG], tx2[TG], ty2[TG], ta[TG];
#pragma unroll
    for (int g = 0; g < TG; ++g) {
        const float tcx = tb[g * 5 + 1], tcy = tb[g * 5 + 2];
        const float tw  = tb[g * 5 + 3], th  = tb[g * 5 + 4];
        tx1[g] = tcx - tw * 0.5f;
        ty1[g] = tcy - th * 0.5f;
        tx2[g] = tcx + tw * 0.5f;
        ty2[g] = tcy + th * 0.5f;
        ta[g]  = (tx2[g] - tx1[g]) * (ty2[g] - ty1[g]);
    }

    // Running best as (numerator, denominator, index); num/den >= 0, den > 0.
    float bn[TG], bd[TG];
    int   bidx[TG];
#pragma unroll
    for (int g = 0; g < TG; ++g) { bn[g] = 0.0f; bd[g] = 1e30f; bidx[g] = 0; }
    // init: ratio 0/1e30 -> loses to anything positive; ties at 0 keep idx 0.
    // (box 0 with inter=0 compares 0*1e30 vs 0*d = tie -> keep idx 0. OK.)

    // 8 boxes per step via 10 aligned float4 loads.
    for (int g0 = tid; g0 < PP / 8; g0 += 256) {
        float4 q[10];
#pragma unroll
        for (int k = 0; k < 10; ++k) q[k] = pb4[g0 * 10 + k];

        float cxs[8], cys[8], wss[8], hss[8];
#pragma unroll
        for (int h = 0; h < 2; ++h) {      // two 4-box halves, same pattern
            const float4 v0 = q[5 * h + 0];
            const float4 v1 = q[5 * h + 1];
            const float4 v2 = q[5 * h + 2];
            const float4 v3 = q[5 * h + 3];
            const float4 v4 = q[5 * h + 4];
            cxs[4 * h + 0] = v0.y; cys[4 * h + 0] = v0.z; wss[4 * h + 0] = v0.w; hss[4 * h + 0] = v1.x;
            cxs[4 * h + 1] = v1.z; cys[4 * h + 1] = v1.w; wss[4 * h + 1] = v2.x; hss[4 * h + 1] = v2.y;
            cxs[4 * h + 2] = v2.w; cys[4 * h + 2] = v3.x; wss[4 * h + 2] = v3.y; hss[4 * h + 2] = v3.z;
            cxs[4 * h + 3] = v4.x; cys[4 * h + 3] = v4.y; wss[4 * h + 3] = v4.z; hss[4 * h + 3] = v4.w;
        }

#pragma unroll
        for (int j = 0; j < 8; ++j) {
            const float px1 = cxs[j] - wss[j] * 0.5f;
            const float py1 = cys[j] - hss[j] * 0.5f;
            const float px2 = cxs[j] + wss[j] * 0.5f;
            const float py2 = cys[j] + hss[j] * 0.5f;
            const float area_p = (px2 - px1) * (py2 - py1);
            const int   p = g0 * 8 + j;

#pragma unroll
            for (int g = 0; g < TG; ++g) {
                const float ix1 = fmaxf(px1, tx1[g]);
                const float iy1 = fmaxf(py1, ty1[g]);
                const float ix2 = fminf(px2, tx2[g]);
                const float iy2 = fminf(py2, ty2[g]);
                const float inter = fmaxf(ix2 - ix1, 0.0f) * fmaxf(iy2 - iy1, 0.0f);
                const float denom = ((area_p + ta[g]) - inter) + 1e-6f;
                // candidate wins iff inter/denom > bn/bd  <=>  inter*bd > bn*denom
                const float lhs = inter * bd[g];
                const float rhs = bn[g] * denom;
                if (lhs > rhs) { bn[g] = inter; bd[g] = denom; bidx[g] = p; }
            }
        }
    }

    // Argmax reduce (cross-mult compare): wave shuffle, then cross-wave LDS.
    __shared__ float s_bn[4][TG];
    __shared__ float s_bd[4][TG];
    __shared__ int   s_bi[4][TG];

#pragma unroll
    for (int g = 0; g < TG; ++g) {
        float n = bn[g], d = bd[g];
        int   i = bidx[g];
        for (int off = 32; off > 0; off >>= 1) {
            const float on = __shfl_down(n, off, 64);
            const float od = __shfl_down(d, off, 64);
            const int   oi = __shfl_down(i, off, 64);
            const float lhs = on * d;
            const float rhs = n * od;
            if (lhs > rhs || (lhs == rhs && oi < i)) { n = on; d = od; i = oi; }
        }
        if (lane == 0) { s_bn[wid][g] = n; s_bd[wid][g] = d; s_bi[wid][g] = i; }
    }
    __syncthreads();

    if (tid < TG) {
        const int g = tid;
        float n = s_bn[0][g], d = s_bd[0][g];
        int   i = s_bi[0][g];
#pragma unroll
        for (int w = 1; w < 4; ++w) {
            const float on = s_bn[w][g];
            const float od = s_bd[w][g];
            const int   oi = s_bi[w][g];
            const float lhs = on * d;
            const float rhs = n * od;
            if (lhs > rhs || (lhs == rhs && oi < i)) { n = on; d = od; i = oi; }
        }
        wsidx[b * TT + t0 + g] = i;
    }
}

// Kernel 2: single block. Gather matched prediction, masked sq error, sum.
__global__ __launch_bounds__(1024) void yolo_finish_kernel(
    const float* __restrict__ pred,
    const float* __restrict__ tgt,
    const int*   __restrict__ lengths,
    const int*   __restrict__ wsidx,
    float*       __restrict__ out)
{
#pragma clang fp contract(off)
    const int tid = threadIdx.x;
    float acc = 0.0f;

    for (int e = tid; e < NE; e += 1024) {
        const int b = e / TT;
        const int t = e - b * TT;
        const int bi = wsidx[e];

        const float* mp = pred + ((size_t)b * PP + bi) * 5;
        const float* tp = tgt  + (size_t)e * 5;
        float sq = 0.0f;
        for (int k = 0; k < 5; ++k) {
            const float d = mp[k] - tp[k];
            sq += d * d;
        }
        acc += (t < lengths[b]) ? sq : 0.0f;
    }

    __shared__ float sm[1024];
    sm[tid] = acc;
    __syncthreads();
    for (int off = 512; off > 0; off >>= 1) {
        if (tid < off) sm[tid] += sm[tid + off];
        __syncthreads();
    }
    if (tid == 0) out[0] = sm[0] / (float)BB;
}

extern "C" void kernel_launch(void* const* d_in, const int* in_sizes, int n_in,
                              void* d_out, int out_size, void* d_ws, size_t ws_size,
                              hipStream_t stream) {
    const float* pred    = (const float*)d_in[0]; // [B,P,5] f32
    const float* tgt     = (const float*)d_in[1]; // [B,T,5] f32
    const int*   lengths = (const int*)d_in[2];   // [B]
    float* out = (float*)d_out;
    int*   wsidx = (int*)d_ws;                    // NE ints = 25.6 KB

    yolo_match_kernel<<<NBLK, 256, 0, stream>>>(pred, tgt, wsidx);
    yolo_finish_kernel<<<1, 1024, 0, stream>>>(pred, tgt, lengths, wsidx, out);
}